// Round 2
// baseline (193.584 us; speedup 1.0000x reference)
//
#include <hip/hip_runtime.h>

#define HH   128
#define WW   128
#define CC   64
#define BB   4
#define TILE 8
#define HALO 12
#define HSTR 72    // ushort stride for halo rows: 144 B = 16B-aligned, bank-rot 4/pixel

typedef unsigned int   uint32;
typedef unsigned short ushort16_t;

// ---- bf16 helpers (bit-level, RNE pack; exact unpack) ----
__device__ __forceinline__ ushort16_t f2bf(float f) {
    union { float f; uint32 i; } u; u.f = f;
    uint32 r = u.i + 0x7fffu + ((u.i >> 16) & 1u);
    return (ushort16_t)(r >> 16);
}
__device__ __forceinline__ uint32 pack2(float a, float b) {
    return (uint32)f2bf(a) | ((uint32)f2bf(b) << 16);
}
__device__ __forceinline__ void bf2f(uint32 u, float& lo, float& hi) {
    union { uint32 i; float f; } a, b;
    a.i = u << 16; b.i = u & 0xffff0000u;
    lo = a.f; hi = b.f;
}
__device__ __forceinline__ void unpack8(uint4 r, float* f) {
    bf2f(r.x, f[0], f[1]); bf2f(r.y, f[2], f[3]);
    bf2f(r.z, f[4], f[5]); bf2f(r.w, f[6], f[7]);
}

// ---------------------------------------------------------------------------
// Kernel A: q = wy*y+by, v = wx*x+bx -> bf16 channel-last ws (b,h,w,c).
// One block = one full (b,h) row of 128 pixels. 256 thr, 8 oc x 4 px / thread.
// ---------------------------------------------------------------------------
__global__ __launch_bounds__(256, 2)
void qv_kernel(const float* __restrict__ x, const float* __restrict__ y,
               const float* __restrict__ wx, const float* __restrict__ bx,
               const float* __restrict__ wy, const float* __restrict__ by,
               ushort16_t* __restrict__ qws, ushort16_t* __restrict__ vws)
{
    __shared__ __align__(16) ushort16_t yls[CC][WW];   // 16 KB bf16 [ic][w]
    __shared__ __align__(16) ushort16_t xls[CC][WW];   // 16 KB
    __shared__ __align__(16) ushort16_t wyT[CC][HSTR]; // 9 KB  [ic][oc]
    __shared__ __align__(16) ushort16_t wxT[CC][HSTR]; // 9 KB

    const int t = threadIdx.x;
    const int h = blockIdx.x;
    const int b = blockIdx.y;

    // ---- stage row tiles (float2 coalesced) + transposed bf16 weights ----
    {
        const int wl  = (t & 63) * 2;
        const int icb = t >> 6;
        #pragma unroll
        for (int i = 0; i < 16; ++i) {
            const int ic = icb + i * 4;
            const size_t base = ((size_t)(b * CC + ic) * HH + h) * WW + wl;
            const float2 yv = *(const float2*)(y + base);
            const float2 xv = *(const float2*)(x + base);
            *(uint32*)&yls[ic][wl] = pack2(yv.x, yv.y);
            *(uint32*)&xls[ic][wl] = pack2(xv.x, xv.y);
        }
        const int ic2 = t & 63;
        const int ocb = t >> 6;
        #pragma unroll
        for (int i = 0; i < 16; ++i) {
            const int oc = ocb + i * 4;
            wyT[ic2][oc] = f2bf(wy[oc * CC + ic2]);
            wxT[ic2][oc] = f2bf(wx[oc * CC + ic2]);
        }
    }
    __syncthreads();

    // ---- main loop: 8 oc x 4 px register block, fp32 accum ----
    const int oc0 = (t & 7) * 8;
    const int wb  = (t >> 3) * 4;

    float aq[8][4] = {{0.f}}, av[8][4] = {{0.f}};
    #pragma unroll 4
    for (int ic = 0; ic < CC; ++ic) {
        const uint2 yr  = *(const uint2*)&yls[ic][wb];
        const uint2 xr  = *(const uint2*)&xls[ic][wb];
        const uint4 wyr = *(const uint4*)&wyT[ic][oc0];
        const uint4 wxr = *(const uint4*)&wxT[ic][oc0];
        float yf[4], xf[4], wyf[8], wxf[8];
        bf2f(yr.x, yf[0], yf[1]); bf2f(yr.y, yf[2], yf[3]);
        bf2f(xr.x, xf[0], xf[1]); bf2f(xr.y, xf[2], xf[3]);
        unpack8(wyr, wyf);
        unpack8(wxr, wxf);
        #pragma unroll
        for (int i = 0; i < 8; ++i)
            #pragma unroll
            for (int j = 0; j < 4; ++j) {
                aq[i][j] += wyf[i] * yf[j];
                av[i][j] += wxf[i] * xf[j];
            }
    }

    // ---- bias + bf16 pack + channel-last store ----
    float byf[8], bxf[8];
    #pragma unroll
    for (int i = 0; i < 8; ++i) { byf[i] = by[oc0 + i]; bxf[i] = bx[oc0 + i]; }
    const size_t ob = (size_t)(b * HH + h) * WW * CC;
    #pragma unroll
    for (int j = 0; j < 4; ++j) {
        uint4 qo, vo;
        qo.x = pack2(aq[0][j] + byf[0], aq[1][j] + byf[1]);
        qo.y = pack2(aq[2][j] + byf[2], aq[3][j] + byf[3]);
        qo.z = pack2(aq[4][j] + byf[4], aq[5][j] + byf[5]);
        qo.w = pack2(aq[6][j] + byf[6], aq[7][j] + byf[7]);
        vo.x = pack2(av[0][j] + bxf[0], av[1][j] + bxf[1]);
        vo.y = pack2(av[2][j] + bxf[2], av[3][j] + bxf[3]);
        vo.z = pack2(av[4][j] + bxf[4], av[5][j] + bxf[5]);
        vo.w = pack2(av[6][j] + bxf[6], av[7][j] + bxf[7]);
        const size_t a = ob + (size_t)(wb + j) * CC + oc0;
        *(uint4*)&qws[a] = qo;
        *(uint4*)&vws[a] = vo;
    }
}

// ---------------------------------------------------------------------------
// Kernel B: scores / softmax / aggregate / final conv + residual.
// 8x8 tile, bf16 halos in LDS, 256 thr, 3 blocks/CU.
// ---------------------------------------------------------------------------
__global__ __launch_bounds__(256, 3)
void attn_kernel(const ushort16_t* __restrict__ qws,
                 const ushort16_t* __restrict__ vws,
                 const float* __restrict__ x, const float* __restrict__ wo,
                 const float* __restrict__ bo, float* __restrict__ out)
{
    __shared__ __align__(16) ushort16_t qh[HALO * HALO][HSTR]; // 20736 B (agg reuses)
    __shared__ __align__(16) ushort16_t vh[HALO * HALO][HSTR]; // 20736 B
    __shared__ __align__(16) ushort16_t woL[CC * CC];          // 8192 B [oc][ic]

    const int t   = threadIdx.x;
    const int b   = blockIdx.z;
    const int ty0 = blockIdx.y * TILE;
    const int tx0 = blockIdx.x * TILE;

    // ---- stage bf16 q/v halo (zero OOB == zero-padded unfold) + weights ----
    for (int i = t; i < HALO * HALO * 8; i += 256) {
        const int pix  = i >> 3, part = i & 7;
        const int hy   = pix / HALO;
        const int hx   = pix - hy * HALO;
        const int gy   = ty0 + hy - 2, gx = tx0 + hx - 2;
        uint4 q4 = {0u, 0u, 0u, 0u}, v4 = {0u, 0u, 0u, 0u};
        if ((unsigned)gy < HH && (unsigned)gx < WW) {
            const size_t a = ((size_t)(b * HH + gy) * WW + gx) * CC + part * 8;
            q4 = *(const uint4*)(qws + a);
            v4 = *(const uint4*)(vws + a);
        }
        *(uint4*)&qh[pix][part * 8] = q4;
        *(uint4*)&vh[pix][part * 8] = v4;
    }
    for (int i = t; i < CC * CC; i += 256) woL[i] = f2bf(wo[i]);
    __syncthreads();

    // ---- scores: 4 lanes/pixel, 16 channels each ----
    const int p    = t >> 2, sub = t & 3;
    const int py   = p >> 3, px  = p & 7;
    const int crow = (py + 2) * HALO + (px + 2);
    const int c0   = sub * 16;

    float qc[16];
    {
        const uint4 r0 = *(const uint4*)&qh[crow][c0];
        const uint4 r1 = *(const uint4*)&qh[crow][c0 + 8];
        unpack8(r0, qc); unpack8(r1, qc + 8);
    }

    float sc[25];
    #pragma unroll
    for (int dy = 0; dy < 5; ++dy)
        #pragma unroll
        for (int dx = 0; dx < 5; ++dx) {
            const ushort16_t* qn = &qh[(py + dy) * HALO + (px + dx)][c0];
            const uint4 r0 = *(const uint4*)qn;
            const uint4 r1 = *(const uint4*)(qn + 8);
            float qf[16]; unpack8(r0, qf); unpack8(r1, qf + 8);
            float s = 0.f;
            #pragma unroll
            for (int j = 0; j < 16; ++j) s += qc[j] * qf[j];
            s += __shfl_xor(s, 1);
            s += __shfl_xor(s, 2);       // consistent across the 4 sub-lanes
            sc[dy * 5 + dx] = s;
        }

    // ---- softmax over 25 ----
    float mx = sc[0];
    #pragma unroll
    for (int k = 1; k < 25; ++k) mx = fmaxf(mx, sc[k]);
    float sum = 0.f;
    #pragma unroll
    for (int k = 0; k < 25; ++k) { sc[k] = __expf(sc[k] - mx); sum += sc[k]; }
    const float inv = 1.f / sum;

    // ---- aggregate v ----
    float ag[16];
    #pragma unroll
    for (int j = 0; j < 16; ++j) ag[j] = 0.f;
    #pragma unroll
    for (int dy = 0; dy < 5; ++dy)
        #pragma unroll
        for (int dx = 0; dx < 5; ++dx) {
            const float a = sc[dy * 5 + dx] * inv;
            const ushort16_t* vn = &vh[(py + dy) * HALO + (px + dx)][c0];
            const uint4 r0 = *(const uint4*)vn;
            const uint4 r1 = *(const uint4*)(vn + 8);
            float vf[16]; unpack8(r0, vf); unpack8(r1, vf + 8);
            #pragma unroll
            for (int j = 0; j < 16; ++j) ag[j] += a * vf[j];
        }

    // ---- agg -> LDS (reuse qh region as fp32 [64][68]) ----
    __syncthreads();
    float* aggF = (float*)&qh[0][0];
    #pragma unroll
    for (int j2 = 0; j2 < 4; ++j2) {
        float4 t4 = { ag[4*j2], ag[4*j2+1], ag[4*j2+2], ag[4*j2+3] };
        *(float4*)&aggF[p * 68 + c0 + 4 * j2] = t4;
    }
    __syncthreads();

    // ---- final 1x1 conv + residual: lane = pixel, wave-uniform oc-block ----
    const int pp  = t & 63;
    const int ob2 = t >> 6;
    float acc[16];
    #pragma unroll
    for (int o = 0; o < 16; ++o) acc[o] = bo[ob2 * 16 + o];
    #pragma unroll
    for (int c4 = 0; c4 < 16; ++c4) {
        const float4 a4 = *(const float4*)&aggF[pp * 68 + c4 * 4];
        #pragma unroll
        for (int o = 0; o < 16; ++o) {
            const uint2 wr = *(const uint2*)&woL[(ob2 * 16 + o) * CC + c4 * 4];
            float w0, w1, w2, w3;
            bf2f(wr.x, w0, w1); bf2f(wr.y, w2, w3);
            acc[o] += a4.x * w0 + a4.y * w1 + a4.z * w2 + a4.w * w3;
        }
    }
    const int gh = ty0 + (pp >> 3), gw = tx0 + (pp & 7);
    #pragma unroll
    for (int o = 0; o < 16; ++o) {
        const int oc = ob2 * 16 + o;
        const size_t a = ((size_t)(b * CC + oc) * HH + gh) * WW + gw;
        out[a] = acc[o] + x[a];
    }
}

// ---------------------------------------------------------------------------
extern "C" void kernel_launch(void* const* d_in, const int* in_sizes, int n_in,
                              void* d_out, int out_size, void* d_ws, size_t ws_size,
                              hipStream_t stream) {
    const float* x  = (const float*)d_in[0];
    const float* y  = (const float*)d_in[1];
    const float* wx = (const float*)d_in[2];
    const float* bx = (const float*)d_in[3];
    const float* wy = (const float*)d_in[4];
    const float* by = (const float*)d_in[5];
    const float* wo = (const float*)d_in[6];
    const float* bo = (const float*)d_in[7];
    float* out = (float*)d_out;

    ushort16_t* qws = (ushort16_t*)d_ws;                          // 8 MB bf16
    ushort16_t* vws = qws + (size_t)BB * HH * WW * CC;            // +8 MB

    dim3 gA(HH, BB);                     // 512 blocks, 1 row each
    qv_kernel<<<gA, 256, 0, stream>>>(x, y, wx, bx, wy, by, qws, vws);

    dim3 gB(WW / TILE, HH / TILE, BB);   // 1024 blocks
    attn_kernel<<<gB, 256, 0, stream>>>(qws, vws, x, wo, bo, out);
}

// Round 4
// 133.764 us; speedup vs baseline: 1.4472x; 1.4472x over previous
//
#include <hip/hip_runtime.h>

#define HH   128
#define WW   128
#define HW   (HH * WW)
#define CC   64
#define BB   4
#define TILE 8
#define HALO 12

typedef unsigned int uint32;
typedef _Float16 h2  __attribute__((ext_vector_type(2)));  // arithmetic (v_pk_fma_f16)
typedef __fp16   h2b __attribute__((ext_vector_type(2)));  // builtin interop type

// f32,f32 -> packed f16 (v_cvt_pkrtz_f16_f32, single instr)
__device__ __forceinline__ uint32 pkrtz(float a, float b) {
    h2b r = __builtin_amdgcn_cvt_pkrtz(a, b);
    return __builtin_bit_cast(uint32, r);
}
// fp32-accumulating packed-f16 dot: v_dot2_f32_f16
__device__ __forceinline__ float dot2(uint32 a, uint32 b, float c) {
#if __has_builtin(__builtin_amdgcn_fdot2)
    return __builtin_amdgcn_fdot2(__builtin_bit_cast(h2b, a),
                                  __builtin_bit_cast(h2b, b), c, false);
#else
    h2 x = __builtin_bit_cast(h2, a), y = __builtin_bit_cast(h2, b);
    return c + (float)x.x * (float)y.x + (float)x.y * (float)y.y;
#endif
}

// ---------------------------------------------------------------------------
// Kernel A: q = wy*y+by, v = wx*x+bx -> f16-pair channel-last ws.
// Block = 64 px. LDS 32 KB -> 4+ blocks/CU. 4 oc x 4 px per thread, fdot2.
// ---------------------------------------------------------------------------
__global__ __launch_bounds__(256, 4)
void qv_kernel(const float* __restrict__ x, const float* __restrict__ y,
               const float* __restrict__ wx, const float* __restrict__ bx,
               const float* __restrict__ wy, const float* __restrict__ by,
               uint32* __restrict__ qws, uint32* __restrict__ vws)
{
    __shared__ uint32 yP[32 * 64];   // [icp][px] f16 pair (ic=2icp, 2icp+1)
    __shared__ uint32 xP[32 * 64];
    __shared__ uint32 wyP[32 * 64];  // [icp][oc]
    __shared__ uint32 wxP[32 * 64];

    const int t  = threadIdx.x;
    const int w0 = blockIdx.x * 64;
    const int h  = blockIdx.y;
    const int b  = blockIdx.z;

    // ---- stage pixels (coalesced plane loads) + weights, f16-packed ----
    {
        const int px = t & 63;
        const size_t rb = (size_t)b * CC * HW + (size_t)h * WW + w0 + px;
        #pragma unroll
        for (int i = 0; i < 8; ++i) {
            const int icp = (t >> 6) * 8 + i;
            const float y0 = y[rb + (size_t)(2 * icp) * HW];
            const float y1 = y[rb + (size_t)(2 * icp + 1) * HW];
            const float x0 = x[rb + (size_t)(2 * icp) * HW];
            const float x1 = x[rb + (size_t)(2 * icp + 1) * HW];
            yP[icp * 64 + px] = pkrtz(y0, y1);
            xP[icp * 64 + px] = pkrtz(x0, x1);
        }
        const int oc = t & 63;
        #pragma unroll
        for (int i = 0; i < 8; ++i) {
            const int icp = (t >> 6) * 8 + i;
            wyP[icp * 64 + oc] = pkrtz(wy[oc * CC + 2 * icp], wy[oc * CC + 2 * icp + 1]);
            wxP[icp * 64 + oc] = pkrtz(wx[oc * CC + 2 * icp], wx[oc * CC + 2 * icp + 1]);
        }
    }
    __syncthreads();

    // ---- 4 oc x 4 px, fdot2 over ic-pairs ----
    const int oc0 = (t & 15) * 4;
    const int px0 = (t >> 4) * 4;

    float aq[4][4] = {{0.f}}, av[4][4] = {{0.f}};
    #pragma unroll 8
    for (int icp = 0; icp < 32; ++icp) {
        const uint4 yv = *(const uint4*)&yP[icp * 64 + px0];
        const uint4 xv = *(const uint4*)&xP[icp * 64 + px0];
        const uint4 wq = *(const uint4*)&wyP[icp * 64 + oc0];
        const uint4 wv = *(const uint4*)&wxP[icp * 64 + oc0];
        const uint32 yf[4] = {yv.x, yv.y, yv.z, yv.w};
        const uint32 xf[4] = {xv.x, xv.y, xv.z, xv.w};
        const uint32 wqf[4] = {wq.x, wq.y, wq.z, wq.w};
        const uint32 wvf[4] = {wv.x, wv.y, wv.z, wv.w};
        #pragma unroll
        for (int i = 0; i < 4; ++i)
            #pragma unroll
            for (int j = 0; j < 4; ++j) {
                aq[i][j] = dot2(wqf[i], yf[j], aq[i][j]);
                av[i][j] = dot2(wvf[i], xf[j], av[i][j]);
            }
    }

    // ---- bias + f16 pack + channel-last store (pairs over oc) ----
    float byf[4], bxf[4];
    #pragma unroll
    for (int i = 0; i < 4; ++i) { byf[i] = by[oc0 + i]; bxf[i] = bx[oc0 + i]; }
    const size_t ob = ((size_t)(b * HH + h) * WW + w0) * 32;  // uint32 units
    #pragma unroll
    for (int j = 0; j < 4; ++j) {
        uint2 qo, vo;
        qo.x = pkrtz(aq[0][j] + byf[0], aq[1][j] + byf[1]);
        qo.y = pkrtz(aq[2][j] + byf[2], aq[3][j] + byf[3]);
        vo.x = pkrtz(av[0][j] + bxf[0], av[1][j] + bxf[1]);
        vo.y = pkrtz(av[2][j] + bxf[2], av[3][j] + bxf[3]);
        const size_t a = ob + (size_t)(px0 + j) * 32 + (oc0 >> 1);
        *(uint2*)&qws[a] = qo;
        *(uint2*)&vws[a] = vo;
    }
}

// ---------------------------------------------------------------------------
// Kernel B: scores/softmax/aggregate/conv+residual. f16 halos, XOR-swizzled
// 128B rows, LDS 36.9 KB -> 4 blocks/CU.
// ---------------------------------------------------------------------------
__global__ __launch_bounds__(256, 4)
void attn_kernel(const uint32* __restrict__ qws, const uint32* __restrict__ vws,
                 const float* __restrict__ x, const float* __restrict__ wo,
                 const float* __restrict__ bo, float* __restrict__ out)
{
    __shared__ uint32 qh[HALO * HALO * 32];  // rows 0..143; later: agg rows 0..63, woP rows 64..127
    __shared__ uint32 vh[HALO * HALO * 32];

    const int t   = threadIdx.x;
    const int b   = blockIdx.z;
    const int ty0 = blockIdx.y * TILE;
    const int tx0 = blockIdx.x * TILE;

    // ---- prefetch wo into regs (f16 pairs), overlaps staging ----
    uint32 wpre[8];
    #pragma unroll
    for (int n = 0; n < 8; ++n) {
        const int k = n * 256 + t;            // k = oc*32 + icp
        const int oc = k >> 5, icp = k & 31;
        wpre[n] = pkrtz(wo[oc * CC + 2 * icp], wo[oc * CC + 2 * icp + 1]);
    }

    // ---- stage q/v halo, swizzled: phys_chunk = part ^ (pix&7) ----
    for (int i = t; i < HALO * HALO * 8; i += 256) {
        const int pix  = i >> 3, part = i & 7;
        const int phys = part ^ (pix & 7);
        const int hy   = pix / HALO;
        const int hx   = pix - hy * HALO;
        const int gy   = ty0 + hy - 2, gx = tx0 + hx - 2;
        uint4 q4 = {0u, 0u, 0u, 0u}, v4 = {0u, 0u, 0u, 0u};
        if ((unsigned)gy < HH && (unsigned)gx < WW) {
            const size_t a = ((size_t)(b * HH + gy) * WW + gx) * 32 + part * 4;
            q4 = *(const uint4*)(qws + a);
            v4 = *(const uint4*)(vws + a);
        }
        *(uint4*)&qh[pix * 32 + phys * 4] = q4;
        *(uint4*)&vh[pix * 32 + phys * 4] = v4;
    }
    __syncthreads();

    // ---- scores: 4 lanes/px, 16 ch each, fdot2 ----
    const int p    = t >> 2, sub = t & 3;
    const int py   = p >> 3, px  = p & 7;
    const int crow = (py + 2) * HALO + (px + 2);

    uint32 qc[8];
    {
        const int c0 = ((2 * sub) ^ (crow & 7)) * 4;
        const int c1 = ((2 * sub + 1) ^ (crow & 7)) * 4;
        *(uint4*)&qc[0] = *(const uint4*)&qh[crow * 32 + c0];
        *(uint4*)&qc[4] = *(const uint4*)&qh[crow * 32 + c1];
    }

    float sc[25];
    #pragma unroll
    for (int dy = 0; dy < 5; ++dy)
        #pragma unroll
        for (int dx = 0; dx < 5; ++dx) {
            const int nrow = (py + dy) * HALO + (px + dx);
            const int c0 = ((2 * sub) ^ (nrow & 7)) * 4;
            const int c1 = ((2 * sub + 1) ^ (nrow & 7)) * 4;
            const uint4 r0 = *(const uint4*)&qh[nrow * 32 + c0];
            const uint4 r1 = *(const uint4*)&qh[nrow * 32 + c1];
            float s = 0.f;
            s = dot2(qc[0], r0.x, s); s = dot2(qc[1], r0.y, s);
            s = dot2(qc[2], r0.z, s); s = dot2(qc[3], r0.w, s);
            s = dot2(qc[4], r1.x, s); s = dot2(qc[5], r1.y, s);
            s = dot2(qc[6], r1.z, s); s = dot2(qc[7], r1.w, s);
            s += __shfl_xor(s, 1);
            s += __shfl_xor(s, 2);          // identical across the 4 sub-lanes
            sc[dy * 5 + dx] = s;
        }

    // ---- softmax over 25 ----
    float mx = sc[0];
    #pragma unroll
    for (int k = 1; k < 25; ++k) mx = fmaxf(mx, sc[k]);
    float sum = 0.f;
    #pragma unroll
    for (int k = 0; k < 25; ++k) { sc[k] = __expf(sc[k] - mx); sum += sc[k]; }
    const float inv = 1.f / sum;

    // ---- aggregate v: packed-f16 accumulate (v_pk_fma_f16) ----
    h2 ag[8];
    #pragma unroll
    for (int k = 0; k < 8; ++k) ag[k] = (h2)(_Float16)0;
    #pragma unroll
    for (int dy = 0; dy < 5; ++dy)
        #pragma unroll
        for (int dx = 0; dx < 5; ++dx) {
            const int nrow = (py + dy) * HALO + (px + dx);
            const int c0 = ((2 * sub) ^ (nrow & 7)) * 4;
            const int c1 = ((2 * sub + 1) ^ (nrow & 7)) * 4;
            const uint4 r0 = *(const uint4*)&vh[nrow * 32 + c0];
            const uint4 r1 = *(const uint4*)&vh[nrow * 32 + c1];
            const _Float16 af = (_Float16)(sc[dy * 5 + dx] * inv);
            const h2 a2 = {af, af};
            ag[0] += a2 * __builtin_bit_cast(h2, r0.x);
            ag[1] += a2 * __builtin_bit_cast(h2, r0.y);
            ag[2] += a2 * __builtin_bit_cast(h2, r0.z);
            ag[3] += a2 * __builtin_bit_cast(h2, r0.w);
            ag[4] += a2 * __builtin_bit_cast(h2, r1.x);
            ag[5] += a2 * __builtin_bit_cast(h2, r1.y);
            ag[6] += a2 * __builtin_bit_cast(h2, r1.z);
            ag[7] += a2 * __builtin_bit_cast(h2, r1.w);
        }

    // ---- overwrite qh: agg rows 0..63 (swizzled), woP rows 64..127 ----
    __syncthreads();
    {
        const int c0 = ((2 * sub) ^ (p & 7)) * 4;
        const int c1 = ((2 * sub + 1) ^ (p & 7)) * 4;
        uint4 w0, w1;
        w0.x = __builtin_bit_cast(uint32, ag[0]); w0.y = __builtin_bit_cast(uint32, ag[1]);
        w0.z = __builtin_bit_cast(uint32, ag[2]); w0.w = __builtin_bit_cast(uint32, ag[3]);
        w1.x = __builtin_bit_cast(uint32, ag[4]); w1.y = __builtin_bit_cast(uint32, ag[5]);
        w1.z = __builtin_bit_cast(uint32, ag[6]); w1.w = __builtin_bit_cast(uint32, ag[7]);
        *(uint4*)&qh[p * 32 + c0] = w0;
        *(uint4*)&qh[p * 32 + c1] = w1;
        #pragma unroll
        for (int n = 0; n < 8; ++n)
            qh[64 * 32 + n * 256 + t] = wpre[n];  // word = 2048 + oc*32 + icp
    }
    __syncthreads();

    // ---- final conv + residual: lane = pixel, wave = 16-oc block ----
    const int pp  = t & 63;
    const int ob2 = t >> 6;
    uint32 aggv[8 * 4];
    #pragma unroll
    for (int j = 0; j < 8; ++j)
        *(uint4*)&aggv[j * 4] = *(const uint4*)&qh[pp * 32 + (j ^ (pp & 7)) * 4];

    const int gh = ty0 + (pp >> 3), gw = tx0 + (pp & 7);
    #pragma unroll
    for (int o = 0; o < 16; ++o) {
        const int oc = ob2 * 16 + o;
        float acc = bo[oc];
        const uint32* wrow = &qh[(64 + oc) * 32];   // wave-uniform -> broadcast
        #pragma unroll
        for (int k = 0; k < 32; ++k) acc = dot2(aggv[k], wrow[k], acc);
        const size_t a = ((size_t)(b * CC + oc) * HH + gh) * WW + gw;
        out[a] = acc + x[a];
    }
}

// ---------------------------------------------------------------------------
extern "C" void kernel_launch(void* const* d_in, const int* in_sizes, int n_in,
                              void* d_out, int out_size, void* d_ws, size_t ws_size,
                              hipStream_t stream) {
    const float* x  = (const float*)d_in[0];
    const float* y  = (const float*)d_in[1];
    const float* wx = (const float*)d_in[2];
    const float* bx = (const float*)d_in[3];
    const float* wy = (const float*)d_in[4];
    const float* by = (const float*)d_in[5];
    const float* wo = (const float*)d_in[6];
    const float* bo = (const float*)d_in[7];
    float* out = (float*)d_out;

    uint32* qws = (uint32*)d_ws;                     // 8 MB (f16 pairs)
    uint32* vws = qws + (size_t)BB * HW * 32;        // +8 MB

    dim3 gA(WW / 64, HH, BB);            // 1024 blocks, 64 px each
    qv_kernel<<<gA, 256, 0, stream>>>(x, y, wx, bx, wy, by, qws, vws);

    dim3 gB(WW / TILE, HH / TILE, BB);   // 1024 blocks
    attn_kernel<<<gB, 256, 0, stream>>>(qws, vws, x, wo, bo, out);
}